// Round 8
// baseline (192.126 us; speedup 1.0000x reference)
//
#include <hip/hip_runtime.h>
#include <math.h>

#define NROWS 16384   // B*M
#define NN 32
#define NC 256
#define ND 128
#define RB 8          // rows per block (4 waves x 2 rows, fully independent)
#define LNEPS 1e-5f
#define SCALE 0.08838834764831845f  // 1/sqrt(128)

typedef float vfloat4 __attribute__((ext_vector_type(4)));

// workspace float offsets
#define OFF_MT   0                      // Mt[c*256+j] = M''[j,c]   (65536)
#define OFF_UVEC 65536                  // uvec_j = sum_c M''[j,c]  (256)
#define OFF_VV   65792                  // vv_j                     (256)
#define OFF_M1   66048                  // m1_c = sum_j M''[j,c]    (256)
#define OFF_WG   66304                  // wg_c = qgamma_c * w_c    (256)
#define OFF_SCAL 66560                  // [sgw, sbw_full, su, svv] (8)

// ---------------- K0a: M''[j,c] = kg_j*qg_c*sum_d Wk[j,d]Wq[c,d]; uvec, vv(part) ----------------
__global__ __launch_bounds__(256)
void ca_prep_a(const float* __restrict__ Wq, const float* __restrict__ Wk,
               const float* __restrict__ qg, const float* __restrict__ qb,
               const float* __restrict__ kg, float* __restrict__ ws) {
    __shared__ __align__(16) float wkrow[ND];
    __shared__ float red[8];
    const int j = blockIdx.x;
    const int c = threadIdx.x;
    const int lane = c & 63, wv = c >> 6;
    if (c < ND / 4) *(float4*)(wkrow + 4 * c) = *(const float4*)(Wk + j * ND + 4 * c);
    __syncthreads();
    float m = 0.f;
    #pragma unroll 8
    for (int d = 0; d < ND; d += 4) {
        const float4 wq4 = *(const float4*)(Wq + c * ND + d);
        const float4 wk4 = *(const float4*)(wkrow + d);
        m += wq4.x * wk4.x + wq4.y * wk4.y + wq4.z * wk4.z + wq4.w * wk4.w;
    }
    const float kgj = kg[j];
    const float mpp = kgj * qg[c] * m;     // M''[j,c]
    ws[OFF_MT + c * NC + j] = mpp;         // transposed store
    float a = mpp, b = kgj * m * qb[c];
    #pragma unroll
    for (int s = 1; s < 64; s <<= 1) { a += __shfl_xor(a, s, 64); b += __shfl_xor(b, s, 64); }
    if (lane == 0) { red[wv] = a; red[4 + wv] = b; }
    __syncthreads();
    if (c == 0) {
        ws[OFF_UVEC + j] = red[0] + red[1] + red[2] + red[3];
        ws[OFF_VV + j]   = red[4] + red[5] + red[6] + red[7];
    }
}

// ---------------- K0b: m1, h, vv += kg*(Wk bq), wg, scalars ----------------
__global__ __launch_bounds__(256)
void ca_prep_b(const float* __restrict__ Wq, const float* __restrict__ Wk,
               const float* __restrict__ qg, const float* __restrict__ qb,
               const float* __restrict__ kg, const float* __restrict__ kb,
               const float* __restrict__ bq, const float* __restrict__ bk,
               float* __restrict__ ws) {
    __shared__ float h[ND];
    __shared__ float htmp[2][ND];
    __shared__ float red[16];
    const int t = threadIdx.x, lane = t & 63, wv = t >> 6;
    // m1_c = sum_j Mt[c*NC + j]  (contiguous per thread, L2-hot)
    {
        float s = 0.f;
        const float* mrow = ws + OFF_MT + t * NC;
        #pragma unroll 8
        for (int j2 = 0; j2 < NC; j2 += 4) {
            const float4 m4 = *(const float4*)(mrow + j2);
            s += (m4.x + m4.y) + (m4.z + m4.w);
        }
        ws[OFF_M1 + t] = s;
    }
    // h_d = bk_d + sum_j Wk[j,d]*kb_j  (two half-sums)
    {
        const int d = t & (ND - 1), half = t >> 7;
        float s = 0.f;
        #pragma unroll 8
        for (int j = half * 128; j < half * 128 + 128; ++j) s += Wk[j * ND + d] * kb[j];
        htmp[half][d] = s;
    }
    __syncthreads();
    if (t < ND) h[t] = bk[t] + htmp[0][t] + htmp[1][t];
    __syncthreads();
    // vv[j] += kg_j*(Wk bq)_j
    float vvj;
    {
        float s = 0.f;
        #pragma unroll 8
        for (int d = 0; d < ND; d += 4) {
            const float4 w4 = *(const float4*)(Wk + t * ND + d);
            const float4 b4 = *(const float4*)(bq + d);
            s += w4.x * b4.x + w4.y * b4.y + w4.z * b4.z + w4.w * b4.w;
        }
        vvj = ws[OFF_VV + t] + kg[t] * s;
        ws[OFF_VV + t] = vvj;
    }
    // w_c = Wq[c,:].h ; wg, scalar sums
    float w = 0.f;
    #pragma unroll 8
    for (int d = 0; d < ND; d += 4) {
        const float4 w4 = *(const float4*)(Wq + t * ND + d);
        w += w4.x * h[d] + w4.y * h[d + 1] + w4.z * h[d + 2] + w4.w * h[d + 3];
    }
    ws[OFF_WG + t] = qg[t] * w;
    float r0 = qg[t] * w;
    float r1 = qb[t] * w + ((t < ND) ? bq[t] * h[t] : 0.f);
    float r2 = ws[OFF_UVEC + t];
    float r3 = vvj;
    #pragma unroll
    for (int s = 1; s < 64; s <<= 1) {
        r0 += __shfl_xor(r0, s, 64); r1 += __shfl_xor(r1, s, 64);
        r2 += __shfl_xor(r2, s, 64); r3 += __shfl_xor(r3, s, 64);
    }
    if (lane == 0) { red[wv] = r0; red[4 + wv] = r1; red[8 + wv] = r2; red[12 + wv] = r3; }
    __syncthreads();
    if (t == 0) {
        ws[OFF_SCAL + 0] = red[0] + red[1] + red[2] + red[3];
        ws[OFF_SCAL + 1] = red[4] + red[5] + red[6] + red[7];
        ws[OFF_SCAL + 2] = red[8] + red[9] + red[10] + red[11];
        ws[OFF_SCAL + 3] = red[12] + red[13] + red[14] + red[15];
    }
}

// ---------------- Fused main, barrier-free: each wave owns 2 rows end-to-end ----------------
__global__ __launch_bounds__(256, 4)
void ca_main(const float* __restrict__ x, const float* __restrict__ y,
             const float* __restrict__ z, const float* __restrict__ ws,
             float* __restrict__ out) {
    __shared__ __align__(16) float xs[RB * NC];   // 8 KB; per-wave private regions
    const int tid = threadIdx.x;
    const int lane = tid & 63;
    const int wv = tid >> 6;
    const int row0 = blockIdx.x * RB;
    const int rA = 2 * wv, rB = 2 * wv + 1;

    float muA, muB, rstdA, rstdB, cstA, cstB, sgA, sgB;

    // ---- Phase 0 (per wave): stats on its 2 x rows + stage to LDS ----
    {
        const float4 wg4 = *(const float4*)(ws + OFF_WG + 4 * lane);
        const float4 m14 = *(const float4*)(ws + OFF_M1 + 4 * lane);
        const float s0 = ws[OFF_SCAL + 0], s1c = ws[OFF_SCAL + 1];
        const float s2c = ws[OFF_SCAL + 2], s3c = ws[OFF_SCAL + 3];
        #pragma unroll
        for (int jj = 0; jj < 2; ++jj) {
            const int r = 2 * wv + jj;
            const float4 x4 = *(const float4*)(x + (size_t)(row0 + r) * NC + 4 * lane);
            *(float4*)(xs + r * NC + 4 * lane) = x4;
            float a = (x4.x + x4.y) + (x4.z + x4.w);
            float b = x4.x * x4.x + x4.y * x4.y + x4.z * x4.z + x4.w * x4.w;
            float cw = x4.x * wg4.x + x4.y * wg4.y + x4.z * wg4.z + x4.w * wg4.w;
            float dm = x4.x * m14.x + x4.y * m14.y + x4.z * m14.z + x4.w * m14.w;
            #pragma unroll
            for (int s = 1; s < 64; s <<= 1) {
                a += __shfl_xor(a, s, 64); b += __shfl_xor(b, s, 64);
                cw += __shfl_xor(cw, s, 64); dm += __shfl_xor(dm, s, 64);
            }
            const float mu = a * (1.f / NC);
            const float var = b * (1.f / NC) - mu * mu;
            const float rstd = rsqrtf(var + LNEPS);
            if (jj == 0) { muA = mu; rstdA = rstd; cstA = rstd * (cw - mu * s0) + s1c; sgA = rstd * (dm - mu * s2c) + s3c; }
            else         { muB = mu; rstdB = rstd; cstB = rstd * (cw - mu * s0) + s1c; sgB = rstd * (dm - mu * s2c) + s3c; }
        }
    }
    // no barrier: each wave reads only its own xs rows below

    // ---- Phase 1 (per wave): full GEMV over all 256 c for its 2 rows; j = 4*lane+0..3 ----
    vfloat4 gpA, gpB;
    {
        float a0 = 0.f, a1 = 0.f, a2 = 0.f, a3 = 0.f;
        float b0 = 0.f, b1 = 0.f, b2 = 0.f, b3 = 0.f;
        const float* Mt = ws + OFF_MT;
        const float* xsa = xs + rA * NC;
        const float* xsb = xs + rB * NC;
        #pragma unroll 4
        for (int c = 0; c < NC; c += 4) {
            const vfloat4 m0  = *(const vfloat4*)(Mt + (c + 0) * NC + 4 * lane);
            const vfloat4 m1v = *(const vfloat4*)(Mt + (c + 1) * NC + 4 * lane);
            const vfloat4 m2  = *(const vfloat4*)(Mt + (c + 2) * NC + 4 * lane);
            const vfloat4 m3  = *(const vfloat4*)(Mt + (c + 3) * NC + 4 * lane);
            const vfloat4 xa = *(const vfloat4*)(xsa + c);   // LDS broadcast
            const vfloat4 xb = *(const vfloat4*)(xsb + c);
            a0 = fmaf(xa.x, m0.x, fmaf(xa.y, m1v.x, fmaf(xa.z, m2.x, fmaf(xa.w, m3.x, a0))));
            a1 = fmaf(xa.x, m0.y, fmaf(xa.y, m1v.y, fmaf(xa.z, m2.y, fmaf(xa.w, m3.y, a1))));
            a2 = fmaf(xa.x, m0.z, fmaf(xa.y, m1v.z, fmaf(xa.z, m2.z, fmaf(xa.w, m3.z, a2))));
            a3 = fmaf(xa.x, m0.w, fmaf(xa.y, m1v.w, fmaf(xa.z, m2.w, fmaf(xa.w, m3.w, a3))));
            b0 = fmaf(xb.x, m0.x, fmaf(xb.y, m1v.x, fmaf(xb.z, m2.x, fmaf(xb.w, m3.x, b0))));
            b1 = fmaf(xb.x, m0.y, fmaf(xb.y, m1v.y, fmaf(xb.z, m2.y, fmaf(xb.w, m3.y, b1))));
            b2 = fmaf(xb.x, m0.z, fmaf(xb.y, m1v.z, fmaf(xb.z, m2.z, fmaf(xb.w, m3.z, b2))));
            b3 = fmaf(xb.x, m0.w, fmaf(xb.y, m1v.w, fmaf(xb.z, m2.w, fmaf(xb.w, m3.w, b3))));
        }
        // ---- combine in registers: gp = rstd*(t - mu*u) + v ----
        const vfloat4 u4 = *(const vfloat4*)(ws + OFF_UVEC + 4 * lane);
        const vfloat4 v4 = *(const vfloat4*)(ws + OFF_VV + 4 * lane);
        gpA.x = rstdA * (a0 - muA * u4.x) + v4.x;
        gpA.y = rstdA * (a1 - muA * u4.y) + v4.y;
        gpA.z = rstdA * (a2 - muA * u4.z) + v4.z;
        gpA.w = rstdA * (a3 - muA * u4.w) + v4.w;
        gpB.x = rstdB * (b0 - muB * u4.x) + v4.x;
        gpB.y = rstdB * (b1 - muB * u4.y) + v4.y;
        gpB.z = rstdB * (b2 - muB * u4.z) + v4.z;
        gpB.w = rstdB * (b3 - muB * u4.w) + v4.w;
    }

    // ---- Phase 3 (per wave): stream y, 4 groups of 16 lanes, 4-slot pipeline ----
    {
        const int g = lane >> 4;
        const int i = lane & 15;
        const int sig = 8 * g + (lane & 7);
        #pragma unroll 1
        for (int jj = 0; jj < 2; ++jj) {
            const size_t row = (size_t)row0 + 2 * wv + jj;
            const float cst = jj ? cstB : cstA;
            const float sg  = jj ? sgB  : sgA;
            const vfloat4 gp_r = jj ? gpB : gpA;
            // gather gp[4*i + 64*k + t] = gp_r.t from lane i+16k (ds_bpermute, no LDS/barrier)
            vfloat4 g0, g1, g2, g3;
            g0.x = __shfl(gp_r.x, i, 64);      g0.y = __shfl(gp_r.y, i, 64);
            g0.z = __shfl(gp_r.z, i, 64);      g0.w = __shfl(gp_r.w, i, 64);
            g1.x = __shfl(gp_r.x, i + 16, 64); g1.y = __shfl(gp_r.y, i + 16, 64);
            g1.z = __shfl(gp_r.z, i + 16, 64); g1.w = __shfl(gp_r.w, i + 16, 64);
            g2.x = __shfl(gp_r.x, i + 32, 64); g2.y = __shfl(gp_r.y, i + 32, 64);
            g2.z = __shfl(gp_r.z, i + 32, 64); g2.w = __shfl(gp_r.w, i + 32, 64);
            g3.x = __shfl(gp_r.x, i + 48, 64); g3.y = __shfl(gp_r.y, i + 48, 64);
            g3.z = __shfl(gp_r.z, i + 48, 64); g3.w = __shfl(gp_r.w, i + 48, 64);
            const float* kb0 = y + row * (size_t)(NN * NC) + (8 * g) * NC + 4 * i;
            const float zv = z[row * NN + sig];
            float dv = 0.f;
            vfloat4 ya0, yb0, yc0, yd0, ya1, yb1, yc1, yd1;
            vfloat4 ya2, yb2, yc2, yd2, ya3, yb3, yc3, yd3;

#define LOADS(S, K) \
            ya##S = *(const vfloat4*)(kb0 + (K) * NC + 0); \
            yb##S = *(const vfloat4*)(kb0 + (K) * NC + 64); \
            yc##S = *(const vfloat4*)(kb0 + (K) * NC + 128); \
            yd##S = *(const vfloat4*)(kb0 + (K) * NC + 192);

#define REDK(S, K) { \
            float s1 = (((ya##S.x + ya##S.y) + (ya##S.z + ya##S.w)) + ((yb##S.x + yb##S.y) + (yb##S.z + yb##S.w))) \
                     + (((yc##S.x + yc##S.y) + (yc##S.z + yc##S.w)) + ((yd##S.x + yd##S.y) + (yd##S.z + yd##S.w))); \
            float s2 = ya##S.x*ya##S.x + ya##S.y*ya##S.y + ya##S.z*ya##S.z + ya##S.w*ya##S.w \
                     + yb##S.x*yb##S.x + yb##S.y*yb##S.y + yb##S.z*yb##S.z + yb##S.w*yb##S.w \
                     + yc##S.x*yc##S.x + yc##S.y*yc##S.y + yc##S.z*yc##S.z + yc##S.w*yc##S.w \
                     + yd##S.x*yd##S.x + yd##S.y*yd##S.y + yd##S.z*yd##S.z + yd##S.w*yd##S.w; \
            float s3 = ya##S.x*g0.x + ya##S.y*g0.y + ya##S.z*g0.z + ya##S.w*g0.w \
                     + yb##S.x*g1.x + yb##S.y*g1.y + yb##S.z*g1.z + yb##S.w*g1.w \
                     + yc##S.x*g2.x + yc##S.y*g2.y + yc##S.z*g2.z + yc##S.w*g2.w \
                     + yd##S.x*g3.x + yd##S.y*g3.y + yd##S.z*g3.z + yd##S.w*g3.w; \
            _Pragma("unroll") \
            for (int s = 1; s < 16; s <<= 1) { \
                s1 += __shfl_xor(s1, s, 64); \
                s2 += __shfl_xor(s2, s, 64); \
                s3 += __shfl_xor(s3, s, 64); \
            } \
            const float mun = s1 * (1.f / NC); \
            const float varn = s2 * (1.f / NC) - mun * mun; \
            const float rsd = rsqrtf(varn + LNEPS); \
            const float dt = SCALE * (rsd * (s3 - mun * sg) + cst); \
            dv = ((lane & 7) == (K)) ? dt : dv; }

            LOADS(0, 0) LOADS(1, 1) LOADS(2, 2) LOADS(3, 3)
            REDK(0, 0) LOADS(0, 4)
            REDK(1, 1) LOADS(1, 5)
            REDK(2, 2) LOADS(2, 6)
            REDK(3, 3) LOADS(3, 7)
            REDK(0, 4) REDK(1, 5) REDK(2, 6) REDK(3, 7)
#undef LOADS
#undef REDK

            // softmax over 32 keys: 5 folds (mask 8 skipped — lanes l, l^8 hold same key)
            float mx = dv;
            mx = fmaxf(mx, __shfl_xor(mx, 1, 64));
            mx = fmaxf(mx, __shfl_xor(mx, 2, 64));
            mx = fmaxf(mx, __shfl_xor(mx, 4, 64));
            mx = fmaxf(mx, __shfl_xor(mx, 16, 64));
            mx = fmaxf(mx, __shfl_xor(mx, 32, 64));
            const float e = __expf(dv - mx);
            float num = e * zv, den = e;
            num += __shfl_xor(num, 1, 64);  den += __shfl_xor(den, 1, 64);
            num += __shfl_xor(num, 2, 64);  den += __shfl_xor(den, 2, 64);
            num += __shfl_xor(num, 4, 64);  den += __shfl_xor(den, 4, 64);
            num += __shfl_xor(num, 16, 64); den += __shfl_xor(den, 16, 64);
            num += __shfl_xor(num, 32, 64); den += __shfl_xor(den, 32, 64);
            if (lane == 0) out[row] = num / den;
        }
    }
}

extern "C" void kernel_launch(void* const* d_in, const int* in_sizes, int n_in,
                              void* d_out, int out_size, void* d_ws, size_t ws_size,
                              hipStream_t stream) {
    const float* x  = (const float*)d_in[0];
    const float* y  = (const float*)d_in[1];
    const float* z  = (const float*)d_in[2];
    const float* qg = (const float*)d_in[3];
    const float* qb = (const float*)d_in[4];
    const float* Wq = (const float*)d_in[5];
    const float* bq = (const float*)d_in[6];
    const float* kg = (const float*)d_in[7];
    const float* kb = (const float*)d_in[8];
    const float* Wk = (const float*)d_in[9];
    const float* bk = (const float*)d_in[10];
    float* out = (float*)d_out;
    float* ws = (float*)d_ws;

    ca_prep_a<<<NC, 256, 0, stream>>>(Wq, Wk, qg, qb, kg, ws);
    ca_prep_b<<<1, 256, 0, stream>>>(Wq, Wk, qg, qb, kg, kb, bq, bk, ws);
    ca_main<<<NROWS / RB, 256, 0, stream>>>(x, y, z, ws, out);
}

// Round 9
// 159.812 us; speedup vs baseline: 1.2022x; 1.2022x over previous
//
#include <hip/hip_runtime.h>
#include <math.h>

#define NROWS 16384   // B*M
#define NN 32
#define NC 256
#define ND 128
#define RB 8          // rows per block
#define LNEPS 1e-5f
#define SCALE 0.08838834764831845f  // 1/sqrt(128)

typedef float vfloat4 __attribute__((ext_vector_type(4)));

// workspace float offsets
#define OFF_MT   0                      // Mt[c*256+j] = M''[j,c]   (65536)
#define OFF_UVEC 65536                  // uvec_j = sum_c M''[j,c]  (256)
#define OFF_VV   65792                  // vv_j                     (256)
#define OFF_M1   66048                  // m1_c = sum_j M''[j,c]    (256)
#define OFF_WG   66304                  // wg_c = qgamma_c * w_c    (256)
#define OFF_SCAL 66560                  // [sgw, sbw_full, su, svv] (8)

__device__ __forceinline__ void gload16(const float* g, float* l) {
    __builtin_amdgcn_global_load_lds(
        (__attribute__((address_space(1))) void*)(void*)g,
        (__attribute__((address_space(3))) void*)l, 16, 0, 0);
}

// ---------------- K0a: M''[j,c] = kg_j*qg_c*sum_d Wk[j,d]Wq[c,d]; uvec, vv(part) ----------------
__global__ __launch_bounds__(256)
void ca_prep_a(const float* __restrict__ Wq, const float* __restrict__ Wk,
               const float* __restrict__ qg, const float* __restrict__ qb,
               const float* __restrict__ kg, float* __restrict__ ws) {
    __shared__ __align__(16) float wkrow[ND];
    __shared__ float red[8];
    const int j = blockIdx.x;
    const int c = threadIdx.x;
    const int lane = c & 63, wv = c >> 6;
    if (c < ND / 4) *(float4*)(wkrow + 4 * c) = *(const float4*)(Wk + j * ND + 4 * c);
    __syncthreads();
    float m = 0.f;
    #pragma unroll 8
    for (int d = 0; d < ND; d += 4) {
        const float4 wq4 = *(const float4*)(Wq + c * ND + d);
        const float4 wk4 = *(const float4*)(wkrow + d);
        m += wq4.x * wk4.x + wq4.y * wk4.y + wq4.z * wk4.z + wq4.w * wk4.w;
    }
    const float kgj = kg[j];
    const float mpp = kgj * qg[c] * m;     // M''[j,c]
    ws[OFF_MT + c * NC + j] = mpp;         // transposed store
    float a = mpp, b = kgj * m * qb[c];
    #pragma unroll
    for (int s = 1; s < 64; s <<= 1) { a += __shfl_xor(a, s, 64); b += __shfl_xor(b, s, 64); }
    if (lane == 0) { red[wv] = a; red[4 + wv] = b; }
    __syncthreads();
    if (c == 0) {
        ws[OFF_UVEC + j] = red[0] + red[1] + red[2] + red[3];
        ws[OFF_VV + j]   = red[4] + red[5] + red[6] + red[7];
    }
}

// ---------------- K0b: m1, h, vv += kg*(Wk bq), wg, scalars ----------------
__global__ __launch_bounds__(256)
void ca_prep_b(const float* __restrict__ Wq, const float* __restrict__ Wk,
               const float* __restrict__ qg, const float* __restrict__ qb,
               const float* __restrict__ kg, const float* __restrict__ kb,
               const float* __restrict__ bq, const float* __restrict__ bk,
               float* __restrict__ ws) {
    __shared__ float h[ND];
    __shared__ float htmp[2][ND];
    __shared__ float red[16];
    const int t = threadIdx.x, lane = t & 63, wv = t >> 6;
    // m1_c = sum_j Mt[c*NC + j]  (contiguous per thread, L2-hot)
    {
        float s = 0.f;
        const float* mrow = ws + OFF_MT + t * NC;
        #pragma unroll 8
        for (int j2 = 0; j2 < NC; j2 += 4) {
            const float4 m4 = *(const float4*)(mrow + j2);
            s += (m4.x + m4.y) + (m4.z + m4.w);
        }
        ws[OFF_M1 + t] = s;
    }
    // h_d = bk_d + sum_j Wk[j,d]*kb_j  (two half-sums)
    {
        const int d = t & (ND - 1), half = t >> 7;
        float s = 0.f;
        #pragma unroll 8
        for (int j = half * 128; j < half * 128 + 128; ++j) s += Wk[j * ND + d] * kb[j];
        htmp[half][d] = s;
    }
    __syncthreads();
    if (t < ND) h[t] = bk[t] + htmp[0][t] + htmp[1][t];
    __syncthreads();
    // vv[j] += kg_j*(Wk bq)_j
    float vvj;
    {
        float s = 0.f;
        #pragma unroll 8
        for (int d = 0; d < ND; d += 4) {
            const float4 w4 = *(const float4*)(Wk + t * ND + d);
            const float4 b4 = *(const float4*)(bq + d);
            s += w4.x * b4.x + w4.y * b4.y + w4.z * b4.z + w4.w * b4.w;
        }
        vvj = ws[OFF_VV + t] + kg[t] * s;
        ws[OFF_VV + t] = vvj;
    }
    // w_c = Wq[c,:].h ; wg, scalar sums
    float w = 0.f;
    #pragma unroll 8
    for (int d = 0; d < ND; d += 4) {
        const float4 w4 = *(const float4*)(Wq + t * ND + d);
        w += w4.x * h[d] + w4.y * h[d + 1] + w4.z * h[d + 2] + w4.w * h[d + 3];
    }
    ws[OFF_WG + t] = qg[t] * w;
    float r0 = qg[t] * w;
    float r1 = qb[t] * w + ((t < ND) ? bq[t] * h[t] : 0.f);
    float r2 = ws[OFF_UVEC + t];
    float r3 = vvj;
    #pragma unroll
    for (int s = 1; s < 64; s <<= 1) {
        r0 += __shfl_xor(r0, s, 64); r1 += __shfl_xor(r1, s, 64);
        r2 += __shfl_xor(r2, s, 64); r3 += __shfl_xor(r3, s, 64);
    }
    if (lane == 0) { red[wv] = r0; red[4 + wv] = r1; red[8 + wv] = r2; red[12 + wv] = r3; }
    __syncthreads();
    if (t == 0) {
        ws[OFF_SCAL + 0] = red[0] + red[1] + red[2] + red[3];
        ws[OFF_SCAL + 1] = red[4] + red[5] + red[6] + red[7];
        ws[OFF_SCAL + 2] = red[8] + red[9] + red[10] + red[11];
        ws[OFF_SCAL + 3] = red[12] + red[13] + red[14] + red[15];
    }
}

// ---------------- Fused main: stats -> GEMV -> combine -> DMA-staged stream ----------------
__global__ __launch_bounds__(256, 4)
void ca_main(const float* __restrict__ x, const float* __restrict__ y,
             const float* __restrict__ z, const float* __restrict__ ws,
             float* __restrict__ out) {
    __shared__ __align__(16) float xs[RB * NC];       // 8 KB: x rows; reused for gp after phase 2
    __shared__ __align__(16) float tp[4 * RB * NC];   // 32 KB: GEMV partials; reused as 4x8KB stage bufs
    const int tid = threadIdx.x;
    const int lane = tid & 63;
    const int wv = tid >> 6;
    const int row0 = blockIdx.x * RB;

    float mu_[2], rstd_[2], cst_[2], sgr_[2];

    // ---- Phase 0: stats on x (4 reductions) + stage x to LDS ----
    {
        const float4 wg4 = *(const float4*)(ws + OFF_WG + 4 * lane);
        const float4 m14 = *(const float4*)(ws + OFF_M1 + 4 * lane);
        const float s0 = ws[OFF_SCAL + 0], s1c = ws[OFF_SCAL + 1];
        const float s2c = ws[OFF_SCAL + 2], s3c = ws[OFF_SCAL + 3];
        #pragma unroll
        for (int jj = 0; jj < 2; ++jj) {
            const int r = 2 * wv + jj;
            const float4 x4 = *(const float4*)(x + (size_t)(row0 + r) * NC + 4 * lane);
            *(float4*)(xs + r * NC + 4 * lane) = x4;
            float a = (x4.x + x4.y) + (x4.z + x4.w);
            float b = x4.x * x4.x + x4.y * x4.y + x4.z * x4.z + x4.w * x4.w;
            float cw = x4.x * wg4.x + x4.y * wg4.y + x4.z * wg4.z + x4.w * wg4.w;
            float dm = x4.x * m14.x + x4.y * m14.y + x4.z * m14.z + x4.w * m14.w;
            #pragma unroll
            for (int s = 1; s < 64; s <<= 1) {
                a += __shfl_xor(a, s, 64); b += __shfl_xor(b, s, 64);
                cw += __shfl_xor(cw, s, 64); dm += __shfl_xor(dm, s, 64);
            }
            const float mu = a * (1.f / NC);
            const float var = b * (1.f / NC) - mu * mu;
            const float rstd = rsqrtf(var + LNEPS);
            mu_[jj] = mu; rstd_[jj] = rstd;
            cst_[jj] = rstd * (cw - mu * s0) + s1c;
            sgr_[jj] = rstd * (dm - mu * s2c) + s3c;
        }
    }
    __syncthreads();

    // ---- Phase 1: GEMV partials. Wave wv covers c in [64wv,64wv+64); output j = 4*lane+0..3 ----
    {
        float acc[RB][4];
        #pragma unroll
        for (int r = 0; r < RB; ++r) { acc[r][0] = acc[r][1] = acc[r][2] = acc[r][3] = 0.f; }
        const float* Mt = ws + OFF_MT;
        const int cb = 64 * wv;
        #pragma unroll 2
        for (int cc = 0; cc < 64; cc += 4) {
            const int c = cb + cc;
            const float4 m0  = *(const float4*)(Mt + (c + 0) * NC + 4 * lane);
            const float4 m1v = *(const float4*)(Mt + (c + 1) * NC + 4 * lane);
            const float4 m2  = *(const float4*)(Mt + (c + 2) * NC + 4 * lane);
            const float4 m3  = *(const float4*)(Mt + (c + 3) * NC + 4 * lane);
            #pragma unroll
            for (int r = 0; r < RB; ++r) {
                const float4 xv = *(const float4*)(xs + r * NC + c);  // broadcast
                acc[r][0] = fmaf(xv.x, m0.x, fmaf(xv.y, m1v.x, fmaf(xv.z, m2.x, fmaf(xv.w, m3.x, acc[r][0]))));
                acc[r][1] = fmaf(xv.x, m0.y, fmaf(xv.y, m1v.y, fmaf(xv.z, m2.y, fmaf(xv.w, m3.y, acc[r][1]))));
                acc[r][2] = fmaf(xv.x, m0.z, fmaf(xv.y, m1v.z, fmaf(xv.z, m2.z, fmaf(xv.w, m3.z, acc[r][2]))));
                acc[r][3] = fmaf(xv.x, m0.w, fmaf(xv.y, m1v.w, fmaf(xv.z, m2.w, fmaf(xv.w, m3.w, acc[r][3]))));
            }
        }
        #pragma unroll
        for (int r = 0; r < RB; ++r) {
            float4 o; o.x = acc[r][0]; o.y = acc[r][1]; o.z = acc[r][2]; o.w = acc[r][3];
            *(float4*)(tp + (wv * RB + r) * NC + 4 * lane) = o;
        }
    }
    __syncthreads();

    // ---- Phase 2: combine partials -> gp for this wave's rows; store gp in xs (x is dead) ----
    {
        const float4 u4 = *(const float4*)(ws + OFF_UVEC + 4 * lane);
        const float4 v4 = *(const float4*)(ws + OFF_VV + 4 * lane);
        #pragma unroll
        for (int jj = 0; jj < 2; ++jj) {
            const int r = 2 * wv + jj;
            const float4 t0 = *(const float4*)(tp + (0 * RB + r) * NC + 4 * lane);
            const float4 t1 = *(const float4*)(tp + (1 * RB + r) * NC + 4 * lane);
            const float4 t2 = *(const float4*)(tp + (2 * RB + r) * NC + 4 * lane);
            const float4 t3 = *(const float4*)(tp + (3 * RB + r) * NC + 4 * lane);
            const float rstd = rstd_[jj], mu = mu_[jj];
            float4 gp;
            gp.x = rstd * ((t0.x + t1.x + t2.x + t3.x) - mu * u4.x) + v4.x;
            gp.y = rstd * ((t0.y + t1.y + t2.y + t3.y) - mu * u4.y) + v4.y;
            gp.z = rstd * ((t0.z + t1.z + t2.z + t3.z) - mu * u4.z) + v4.z;
            gp.w = rstd * ((t0.w + t1.w + t2.w + t3.w) - mu * u4.w) + v4.w;
            *(float4*)(xs + r * NC + 4 * lane) = gp;   // own rows only (wave-local)
        }
    }

    // ---- Phase 3: stream y via global_load_lds DMA into per-wave 2x4KB buffers ----
    {
        const int g = lane >> 4;
        const int i = lane & 15;
        const int sig = 8 * g + (lane & 7);
        float* stage = tp + wv * 2048;   // 8 KB per wave

        // g-fragments for both rows from xs (wave-local, written by this wave in phase 2)
        const float* glA = xs + (2 * wv + 0) * NC + 4 * i;
        const vfloat4 A0 = *(const vfloat4*)(glA + 0);
        const vfloat4 A1 = *(const vfloat4*)(glA + 64);
        const vfloat4 A2 = *(const vfloat4*)(glA + 128);
        const vfloat4 A3 = *(const vfloat4*)(glA + 192);
        const float* glB = xs + (2 * wv + 1) * NC + 4 * i;
        const vfloat4 B0 = *(const vfloat4*)(glB + 0);
        const vfloat4 B1 = *(const vfloat4*)(glB + 64);
        const vfloat4 B2 = *(const vfloat4*)(glB + 128);
        const vfloat4 B3 = *(const vfloat4*)(glB + 192);
        const float zvA = z[(size_t)(row0 + 2 * wv + 0) * NN + sig];
        const float zvB = z[(size_t)(row0 + 2 * wv + 1) * NN + sig];
        asm volatile("s_waitcnt vmcnt(0)" ::: "memory");   // clean vmcnt before counted waits
        __syncthreads();   // tp slabs were read cross-wave in phase 2; now safe to overwrite

#define STAGE(r, b) { \
            gload16(yrow + (8 * 0 + (r)) * NC + 4 * lane, stage + (b) * 1024 + 0 * 256); \
            gload16(yrow + (8 * 1 + (r)) * NC + 4 * lane, stage + (b) * 1024 + 1 * 256); \
            gload16(yrow + (8 * 2 + (r)) * NC + 4 * lane, stage + (b) * 1024 + 2 * 256); \
            gload16(yrow + (8 * 3 + (r)) * NC + 4 * lane, stage + (b) * 1024 + 3 * 256); }

#define ROUND(K, b, WN, STG) { \
            asm volatile("s_waitcnt vmcnt(" WN ")" ::: "memory"); \
            __builtin_amdgcn_sched_barrier(0); \
            const float* kp = stage + (b) * 1024 + g * 256 + 4 * i; \
            const vfloat4 y0 = *(const vfloat4*)(kp + 0); \
            const vfloat4 y1 = *(const vfloat4*)(kp + 64); \
            const vfloat4 y2 = *(const vfloat4*)(kp + 128); \
            const vfloat4 y3 = *(const vfloat4*)(kp + 192); \
            float s1 = (((y0.x + y0.y) + (y0.z + y0.w)) + ((y1.x + y1.y) + (y1.z + y1.w))) \
                     + (((y2.x + y2.y) + (y2.z + y2.w)) + ((y3.x + y3.y) + (y3.z + y3.w))); \
            float s2 = y0.x*y0.x + y0.y*y0.y + y0.z*y0.z + y0.w*y0.w \
                     + y1.x*y1.x + y1.y*y1.y + y1.z*y1.z + y1.w*y1.w \
                     + y2.x*y2.x + y2.y*y2.y + y2.z*y2.z + y2.w*y2.w \
                     + y3.x*y3.x + y3.y*y3.y + y3.z*y3.z + y3.w*y3.w; \
            float s3 = y0.x*g0.x + y0.y*g0.y + y0.z*g0.z + y0.w*g0.w \
                     + y1.x*g1.x + y1.y*g1.y + y1.z*g1.z + y1.w*g1.w \
                     + y2.x*g2.x + y2.y*g2.y + y2.z*g2.z + y2.w*g2.w \
                     + y3.x*g3.x + y3.y*g3.y + y3.z*g3.z + y3.w*g3.w; \
            __builtin_amdgcn_sched_barrier(0); \
            STG; \
            _Pragma("unroll") \
            for (int s = 1; s < 16; s <<= 1) { \
                s1 += __shfl_xor(s1, s, 64); \
                s2 += __shfl_xor(s2, s, 64); \
                s3 += __shfl_xor(s3, s, 64); \
            } \
            const float mun = s1 * (1.f / NC); \
            const float varn = s2 * (1.f / NC) - mun * mun; \
            const float rsd = rsqrtf(varn + LNEPS); \
            const float dt = SCALE * (rsd * (s3 - mun * sg) + cst); \
            dv = ((lane & 7) == (K)) ? dt : dv; }

        #pragma unroll
        for (int jj = 0; jj < 2; ++jj) {
            const size_t row = (size_t)row0 + 2 * wv + jj;
            const float cst = jj ? cst_[1] : cst_[0];
            const float sg  = jj ? sgr_[1] : sgr_[0];
            const vfloat4 g0 = jj ? B0 : A0;
            const vfloat4 g1 = jj ? B1 : A1;
            const vfloat4 g2 = jj ? B2 : A2;
            const vfloat4 g3 = jj ? B3 : A3;
            const float zv = jj ? zvB : zvA;
            const float* yrow = y + row * (size_t)(NN * NC);
            float dv = 0.f;

            STAGE(0, 0)
            STAGE(1, 1)
            ROUND(0, 0, "4", STAGE(2, 0))
            ROUND(1, 1, "4", STAGE(3, 1))
            ROUND(2, 0, "4", STAGE(4, 0))
            ROUND(3, 1, "4", STAGE(5, 1))
            ROUND(4, 0, "4", STAGE(6, 0))
            ROUND(5, 1, "4", STAGE(7, 1))
            ROUND(6, 0, "4", ((void)0))
            ROUND(7, 1, "0", ((void)0))

            // softmax over 32 keys: 5 folds (mask 8 skipped — lanes l, l^8 hold same key)
            float mx = dv;
            mx = fmaxf(mx, __shfl_xor(mx, 1, 64));
            mx = fmaxf(mx, __shfl_xor(mx, 2, 64));
            mx = fmaxf(mx, __shfl_xor(mx, 4, 64));
            mx = fmaxf(mx, __shfl_xor(mx, 16, 64));
            mx = fmaxf(mx, __shfl_xor(mx, 32, 64));
            const float e = __expf(dv - mx);
            float num = e * zv, den = e;
            num += __shfl_xor(num, 1, 64);  den += __shfl_xor(den, 1, 64);
            num += __shfl_xor(num, 2, 64);  den += __shfl_xor(den, 2, 64);
            num += __shfl_xor(num, 4, 64);  den += __shfl_xor(den, 4, 64);
            num += __shfl_xor(num, 16, 64); den += __shfl_xor(den, 16, 64);
            num += __shfl_xor(num, 32, 64); den += __shfl_xor(den, 32, 64);
            if (lane == 0) out[row] = num / den;
            asm volatile("s_waitcnt vmcnt(0)" ::: "memory");  // drain store before next row's counted waits
        }
#undef STAGE
#undef ROUND
    }
}

extern "C" void kernel_launch(void* const* d_in, const int* in_sizes, int n_in,
                              void* d_out, int out_size, void* d_ws, size_t ws_size,
                              hipStream_t stream) {
    const float* x  = (const float*)d_in[0];
    const float* y  = (const float*)d_in[1];
    const float* z  = (const float*)d_in[2];
    const float* qg = (const float*)d_in[3];
    const float* qb = (const float*)d_in[4];
    const float* Wq = (const float*)d_in[5];
    const float* bq = (const float*)d_in[6];
    const float* kg = (const float*)d_in[7];
    const float* kb = (const float*)d_in[8];
    const float* Wk = (const float*)d_in[9];
    const float* bk = (const float*)d_in[10];
    float* out = (float*)d_out;
    float* ws = (float*)d_ws;

    ca_prep_a<<<NC, 256, 0, stream>>>(Wq, Wk, qg, qb, kg, ws);
    ca_prep_b<<<1, 256, 0, stream>>>(Wq, Wk, qg, qb, kg, kb, bq, bk, ws);
    ca_main<<<NROWS / RB, 256, 0, stream>>>(x, y, z, ws, out);
}

// Round 10
// 149.875 us; speedup vs baseline: 1.2819x; 1.0663x over previous
//
#include <hip/hip_runtime.h>
#include <math.h>

#define NROWS 16384   // B*M
#define NN 32
#define NC 256
#define ND 128
#define RB 8          // rows per block
#define LNEPS 1e-5f
#define SCALE 0.08838834764831845f  // 1/sqrt(128)

typedef float vfloat4 __attribute__((ext_vector_type(4)));

// workspace float offsets
#define OFF_MT   0                      // Mt[c*256+j] = M''[j,c]   (65536)
#define OFF_UVEC 65536                  // uvec_j = sum_c M''[j,c]  (256)
#define OFF_VV   65792                  // vv_j                     (256)
#define OFF_M1   66048                  // m1_c = sum_j M''[j,c]    (256)
#define OFF_WG   66304                  // wg_c = qgamma_c * w_c    (256)
#define OFF_SCAL 66560                  // [sgw, sbw_full, su, svv] (8)

// Sum across each 16-lane row via DPP row_ror (VALU, ~4cy/step; no DS pipe).
// After the 4 rotation-doubling steps every lane holds its 16-lane row total.
__device__ __forceinline__ float red16(float v) {
    int t;
    t = __builtin_amdgcn_update_dpp(0, __float_as_int(v), 0x121, 0xf, 0xf, false); // row_ror:1
    v += __int_as_float(t);
    t = __builtin_amdgcn_update_dpp(0, __float_as_int(v), 0x122, 0xf, 0xf, false); // row_ror:2
    v += __int_as_float(t);
    t = __builtin_amdgcn_update_dpp(0, __float_as_int(v), 0x124, 0xf, 0xf, false); // row_ror:4
    v += __int_as_float(t);
    t = __builtin_amdgcn_update_dpp(0, __float_as_int(v), 0x128, 0xf, 0xf, false); // row_ror:8
    v += __int_as_float(t);
    return v;
}

// ---------------- K0a: M''[j,c] = kg_j*qg_c*sum_d Wk[j,d]Wq[c,d]; uvec, vv(part) ----------------
__global__ __launch_bounds__(256)
void ca_prep_a(const float* __restrict__ Wq, const float* __restrict__ Wk,
               const float* __restrict__ qg, const float* __restrict__ qb,
               const float* __restrict__ kg, float* __restrict__ ws) {
    __shared__ __align__(16) float wkrow[ND];
    __shared__ float red[8];
    const int j = blockIdx.x;
    const int c = threadIdx.x;
    const int lane = c & 63, wv = c >> 6;
    if (c < ND / 4) *(float4*)(wkrow + 4 * c) = *(const float4*)(Wk + j * ND + 4 * c);
    __syncthreads();
    float m = 0.f;
    #pragma unroll 8
    for (int d = 0; d < ND; d += 4) {
        const float4 wq4 = *(const float4*)(Wq + c * ND + d);
        const float4 wk4 = *(const float4*)(wkrow + d);
        m += wq4.x * wk4.x + wq4.y * wk4.y + wq4.z * wk4.z + wq4.w * wk4.w;
    }
    const float kgj = kg[j];
    const float mpp = kgj * qg[c] * m;     // M''[j,c]
    ws[OFF_MT + c * NC + j] = mpp;         // transposed store
    float a = red16(mpp), b = red16(kgj * m * qb[c]);
    a += __shfl_xor(a, 16, 64); b += __shfl_xor(b, 16, 64);
    a += __shfl_xor(a, 32, 64); b += __shfl_xor(b, 32, 64);
    if (lane == 0) { red[wv] = a; red[4 + wv] = b; }
    __syncthreads();
    if (c == 0) {
        ws[OFF_UVEC + j] = red[0] + red[1] + red[2] + red[3];
        ws[OFF_VV + j]   = red[4] + red[5] + red[6] + red[7];
    }
}

// ---------------- K0b: m1, h, vv += kg*(Wk bq), wg, scalars ----------------
__global__ __launch_bounds__(256)
void ca_prep_b(const float* __restrict__ Wq, const float* __restrict__ Wk,
               const float* __restrict__ qg, const float* __restrict__ qb,
               const float* __restrict__ kg, const float* __restrict__ kb,
               const float* __restrict__ bq, const float* __restrict__ bk,
               float* __restrict__ ws) {
    __shared__ float h[ND];
    __shared__ float htmp[2][ND];
    __shared__ float red[16];
    const int t = threadIdx.x, lane = t & 63, wv = t >> 6;
    // m1_c = sum_j Mt[c*NC + j]  (contiguous per thread, L2-hot)
    {
        float s = 0.f;
        const float* mrow = ws + OFF_MT + t * NC;
        #pragma unroll 8
        for (int j2 = 0; j2 < NC; j2 += 4) {
            const float4 m4 = *(const float4*)(mrow + j2);
            s += (m4.x + m4.y) + (m4.z + m4.w);
        }
        ws[OFF_M1 + t] = s;
    }
    // h_d = bk_d + sum_j Wk[j,d]*kb_j  (two half-sums)
    {
        const int d = t & (ND - 1), half = t >> 7;
        float s = 0.f;
        #pragma unroll 8
        for (int j = half * 128; j < half * 128 + 128; ++j) s += Wk[j * ND + d] * kb[j];
        htmp[half][d] = s;
    }
    __syncthreads();
    if (t < ND) h[t] = bk[t] + htmp[0][t] + htmp[1][t];
    __syncthreads();
    // vv[j] += kg_j*(Wk bq)_j
    float vvj;
    {
        float s = 0.f;
        #pragma unroll 8
        for (int d = 0; d < ND; d += 4) {
            const float4 w4 = *(const float4*)(Wk + t * ND + d);
            const float4 b4 = *(const float4*)(bq + d);
            s += w4.x * b4.x + w4.y * b4.y + w4.z * b4.z + w4.w * b4.w;
        }
        vvj = ws[OFF_VV + t] + kg[t] * s;
        ws[OFF_VV + t] = vvj;
    }
    // w_c = Wq[c,:].h ; wg, scalar sums
    float w = 0.f;
    #pragma unroll 8
    for (int d = 0; d < ND; d += 4) {
        const float4 w4 = *(const float4*)(Wq + t * ND + d);
        w += w4.x * h[d] + w4.y * h[d + 1] + w4.z * h[d + 2] + w4.w * h[d + 3];
    }
    ws[OFF_WG + t] = qg[t] * w;
    float r0 = qg[t] * w;
    float r1 = qb[t] * w + ((t < ND) ? bq[t] * h[t] : 0.f);
    float r2 = ws[OFF_UVEC + t];
    float r3 = vvj;
    r0 = red16(r0); r1 = red16(r1); r2 = red16(r2); r3 = red16(r3);
    #pragma unroll
    for (int s = 16; s < 64; s <<= 1) {
        r0 += __shfl_xor(r0, s, 64); r1 += __shfl_xor(r1, s, 64);
        r2 += __shfl_xor(r2, s, 64); r3 += __shfl_xor(r3, s, 64);
    }
    if (lane == 0) { red[wv] = r0; red[4 + wv] = r1; red[8 + wv] = r2; red[12 + wv] = r3; }
    __syncthreads();
    if (t == 0) {
        ws[OFF_SCAL + 0] = red[0] + red[1] + red[2] + red[3];
        ws[OFF_SCAL + 1] = red[4] + red[5] + red[6] + red[7];
        ws[OFF_SCAL + 2] = red[8] + red[9] + red[10] + red[11];
        ws[OFF_SCAL + 3] = red[12] + red[13] + red[14] + red[15];
    }
}

// ---------------- Fused main: stats -> GEMV -> combine -> stream ----------------
__global__ __launch_bounds__(256, 4)
void ca_main(const float* __restrict__ x, const float* __restrict__ y,
             const float* __restrict__ z, const float* __restrict__ ws,
             float* __restrict__ out) {
    __shared__ __align__(16) float xs[RB * NC];       // 8 KB: raw x rows
    __shared__ __align__(16) float tp[4 * RB * NC];   // 32 KB: GEMV partials; tp[0] region reused for gp
    const int tid = threadIdx.x;
    const int lane = tid & 63;
    const int wv = tid >> 6;
    const int row0 = blockIdx.x * RB;

    float mu_[2], rstd_[2], cst_[2], sgr_[2];

    // ---- Phase 0: stats on x (4 reductions) + stage x to LDS ----
    {
        const float4 wg4 = *(const float4*)(ws + OFF_WG + 4 * lane);
        const float4 m14 = *(const float4*)(ws + OFF_M1 + 4 * lane);
        const float s0 = ws[OFF_SCAL + 0], s1c = ws[OFF_SCAL + 1];
        const float s2c = ws[OFF_SCAL + 2], s3c = ws[OFF_SCAL + 3];
        #pragma unroll
        for (int jj = 0; jj < 2; ++jj) {
            const int r = 2 * wv + jj;
            const float4 x4 = *(const float4*)(x + (size_t)(row0 + r) * NC + 4 * lane);
            *(float4*)(xs + r * NC + 4 * lane) = x4;
            float a = (x4.x + x4.y) + (x4.z + x4.w);
            float b = x4.x * x4.x + x4.y * x4.y + x4.z * x4.z + x4.w * x4.w;
            float cw = x4.x * wg4.x + x4.y * wg4.y + x4.z * wg4.z + x4.w * wg4.w;
            float dm = x4.x * m14.x + x4.y * m14.y + x4.z * m14.z + x4.w * m14.w;
            a = red16(a); b = red16(b); cw = red16(cw); dm = red16(dm);
            #pragma unroll
            for (int s = 16; s < 64; s <<= 1) {
                a += __shfl_xor(a, s, 64); b += __shfl_xor(b, s, 64);
                cw += __shfl_xor(cw, s, 64); dm += __shfl_xor(dm, s, 64);
            }
            const float mu = a * (1.f / NC);
            const float var = b * (1.f / NC) - mu * mu;
            const float rstd = rsqrtf(var + LNEPS);
            mu_[jj] = mu; rstd_[jj] = rstd;
            cst_[jj] = rstd * (cw - mu * s0) + s1c;
            sgr_[jj] = rstd * (dm - mu * s2c) + s3c;
        }
    }
    __syncthreads();

    // ---- Phase 1: GEMV partials. Wave wv covers c in [64wv,64wv+64); output j = 4*lane+0..3 ----
    {
        float acc[RB][4];
        #pragma unroll
        for (int r = 0; r < RB; ++r) { acc[r][0] = acc[r][1] = acc[r][2] = acc[r][3] = 0.f; }
        const float* Mt = ws + OFF_MT;
        const int cb = 64 * wv;
        #pragma unroll 2
        for (int cc = 0; cc < 64; cc += 4) {
            const int c = cb + cc;
            const float4 m0  = *(const float4*)(Mt + (c + 0) * NC + 4 * lane);
            const float4 m1v = *(const float4*)(Mt + (c + 1) * NC + 4 * lane);
            const float4 m2  = *(const float4*)(Mt + (c + 2) * NC + 4 * lane);
            const float4 m3  = *(const float4*)(Mt + (c + 3) * NC + 4 * lane);
            #pragma unroll
            for (int r = 0; r < RB; ++r) {
                const float4 xv = *(const float4*)(xs + r * NC + c);  // broadcast
                acc[r][0] = fmaf(xv.x, m0.x, fmaf(xv.y, m1v.x, fmaf(xv.z, m2.x, fmaf(xv.w, m3.x, acc[r][0]))));
                acc[r][1] = fmaf(xv.x, m0.y, fmaf(xv.y, m1v.y, fmaf(xv.z, m2.y, fmaf(xv.w, m3.y, acc[r][1]))));
                acc[r][2] = fmaf(xv.x, m0.z, fmaf(xv.y, m1v.z, fmaf(xv.z, m2.z, fmaf(xv.w, m3.z, acc[r][2]))));
                acc[r][3] = fmaf(xv.x, m0.w, fmaf(xv.y, m1v.w, fmaf(xv.z, m2.w, fmaf(xv.w, m3.w, acc[r][3]))));
            }
        }
        #pragma unroll
        for (int r = 0; r < RB; ++r) {
            float4 o; o.x = acc[r][0]; o.y = acc[r][1]; o.z = acc[r][2]; o.w = acc[r][3];
            *(float4*)(tp + (wv * RB + r) * NC + 4 * lane) = o;
        }
    }
    __syncthreads();

    // ---- Phase 2: combine partials -> gp for this wave's rows; stash gp in tp[0] region ----
    {
        const float4 u4 = *(const float4*)(ws + OFF_UVEC + 4 * lane);
        const float4 v4 = *(const float4*)(ws + OFF_VV + 4 * lane);
        #pragma unroll
        for (int jj = 0; jj < 2; ++jj) {
            const int r = 2 * wv + jj;
            const float4 t0 = *(const float4*)(tp + (0 * RB + r) * NC + 4 * lane);
            const float4 t1 = *(const float4*)(tp + (1 * RB + r) * NC + 4 * lane);
            const float4 t2 = *(const float4*)(tp + (2 * RB + r) * NC + 4 * lane);
            const float4 t3 = *(const float4*)(tp + (3 * RB + r) * NC + 4 * lane);
            const float rstd = rstd_[jj], mu = mu_[jj];
            float4 gp;
            gp.x = rstd * ((t0.x + t1.x + t2.x + t3.x) - mu * u4.x) + v4.x;
            gp.y = rstd * ((t0.y + t1.y + t2.y + t3.y) - mu * u4.y) + v4.y;
            gp.z = rstd * ((t0.z + t1.z + t2.z + t3.z) - mu * u4.z) + v4.z;
            gp.w = rstd * ((t0.w + t1.w + t2.w + t3.w) - mu * u4.w) + v4.w;
            // rows are wave-exclusive in tp[0] region: no barrier needed before/after
            *(float4*)(tp + r * NC + 4 * lane) = gp;
        }
    }

    // ---- Phase 3: stream y. 4 groups of 16 lanes; group g handles keys 8g..8g+7.
    //      4-slot load pipeline; per-key reduce entirely on VALU via DPP row_ror.
    {
        const int g = lane >> 4;
        const int i = lane & 15;
        const int sig = 8 * g + (lane & 7);   // key this lane represents in softmax (2 lanes/key)
        #pragma unroll 1
        for (int jj = 0; jj < 2; ++jj) {
            const int r = 2 * wv + jj;
            const size_t row = (size_t)row0 + r;
            const float* gl = tp + r * NC + 4 * i;
            const vfloat4 g0 = *(const vfloat4*)(gl + 0);
            const vfloat4 g1 = *(const vfloat4*)(gl + 64);
            const vfloat4 g2 = *(const vfloat4*)(gl + 128);
            const vfloat4 g3 = *(const vfloat4*)(gl + 192);
            const float cst = cst_[jj], sg = sgr_[jj];
            const float* kb0 = y + row * (size_t)(NN * NC) + (8 * g) * NC + 4 * i;
            const float zv = z[row * NN + sig];
            float dv = 0.f;
            vfloat4 ya0, yb0, yc0, yd0, ya1, yb1, yc1, yd1;
            vfloat4 ya2, yb2, yc2, yd2, ya3, yb3, yc3, yd3;

#define LOADS(S, K) \
            ya##S = *(const vfloat4*)(kb0 + (K) * NC + 0); \
            yb##S = *(const vfloat4*)(kb0 + (K) * NC + 64); \
            yc##S = *(const vfloat4*)(kb0 + (K) * NC + 128); \
            yd##S = *(const vfloat4*)(kb0 + (K) * NC + 192);

#define REDK(S, K) { \
            float s1 = (((ya##S.x + ya##S.y) + (ya##S.z + ya##S.w)) + ((yb##S.x + yb##S.y) + (yb##S.z + yb##S.w))) \
                     + (((yc##S.x + yc##S.y) + (yc##S.z + yc##S.w)) + ((yd##S.x + yd##S.y) + (yd##S.z + yd##S.w))); \
            float s2 = ya##S.x*ya##S.x + ya##S.y*ya##S.y + ya##S.z*ya##S.z + ya##S.w*ya##S.w \
                     + yb##S.x*yb##S.x + yb##S.y*yb##S.y + yb##S.z*yb##S.z + yb##S.w*yb##S.w \
                     + yc##S.x*yc##S.x + yc##S.y*yc##S.y + yc##S.z*yc##S.z + yc##S.w*yc##S.w \
                     + yd##S.x*yd##S.x + yd##S.y*yd##S.y + yd##S.z*yd##S.z + yd##S.w*yd##S.w; \
            float s3 = ya##S.x*g0.x + ya##S.y*g0.y + ya##S.z*g0.z + ya##S.w*g0.w \
                     + yb##S.x*g1.x + yb##S.y*g1.y + yb##S.z*g1.z + yb##S.w*g1.w \
                     + yc##S.x*g2.x + yc##S.y*g2.y + yc##S.z*g2.z + yc##S.w*g2.w \
                     + yd##S.x*g3.x + yd##S.y*g3.y + yd##S.z*g3.z + yd##S.w*g3.w; \
            s1 = red16(s1); s2 = red16(s2); s3 = red16(s3); \
            const float mun = s1 * (1.f / NC); \
            const float varn = s2 * (1.f / NC) - mun * mun; \
            const float rsd = rsqrtf(varn + LNEPS); \
            const float dt = SCALE * (rsd * (s3 - mun * sg) + cst); \
            dv = ((lane & 7) == (K)) ? dt : dv; }

            LOADS(0, 0) LOADS(1, 1) LOADS(2, 2) LOADS(3, 3)
            REDK(0, 0) LOADS(0, 4)
            REDK(1, 1) LOADS(1, 5)
            REDK(2, 2) LOADS(2, 6)
            REDK(3, 3) LOADS(3, 7)
            REDK(0, 4) REDK(1, 5) REDK(2, 6) REDK(3, 7)
#undef LOADS
#undef REDK

            // softmax over 32 keys: 5 folds (mask 8 skipped — lanes l, l^8 hold same key)
            float mx = dv;
            mx = fmaxf(mx, __shfl_xor(mx, 1, 64));
            mx = fmaxf(mx, __shfl_xor(mx, 2, 64));
            mx = fmaxf(mx, __shfl_xor(mx, 4, 64));
            mx = fmaxf(mx, __shfl_xor(mx, 16, 64));
            mx = fmaxf(mx, __shfl_xor(mx, 32, 64));
            const float e = __expf(dv - mx);
            float num = e * zv, den = e;
            num += __shfl_xor(num, 1, 64);  den += __shfl_xor(den, 1, 64);
            num += __shfl_xor(num, 2, 64);  den += __shfl_xor(den, 2, 64);
            num += __shfl_xor(num, 4, 64);  den += __shfl_xor(den, 4, 64);
            num += __shfl_xor(num, 16, 64); den += __shfl_xor(den, 16, 64);
            num += __shfl_xor(num, 32, 64); den += __shfl_xor(den, 32, 64);
            if (lane == 0) out[row] = num / den;
        }
    }
}

extern "C" void kernel_launch(void* const* d_in, const int* in_sizes, int n_in,
                              void* d_out, int out_size, void* d_ws, size_t ws_size,
                              hipStream_t stream) {
    const float* x  = (const float*)d_in[0];
    const float* y  = (const float*)d_in[1];
    const float* z  = (const float*)d_in[2];
    const float* qg = (const float*)d_in[3];
    const float* qb = (const float*)d_in[4];
    const float* Wq = (const float*)d_in[5];
    const float* bq = (const float*)d_in[6];
    const float* kg = (const float*)d_in[7];
    const float* kb = (const float*)d_in[8];
    const float* Wk = (const float*)d_in[9];
    const float* bk = (const float*)d_in[10];
    float* out = (float*)d_out;
    float* ws = (float*)d_ws;

    ca_prep_a<<<NC, 256, 0, stream>>>(Wq, Wk, qg, qb, kg, ws);
    ca_prep_b<<<1, 256, 0, stream>>>(Wq, Wk, qg, qb, kg, kb, bq, bk, ws);
    ca_main<<<NROWS / RB, 256, 0, stream>>>(x, y, z, ws, out);
}